// Round 8
// baseline (59.180 us; speedup 1.0000x reference)
//
#include <hip/hip_runtime.h>

// ROI pooling: bilinear resize each (h,w) crop to 7x7 over 256 channels.
// img: (200,200,256) f32 NHWC; rois: (2000,4) int32 (x,y,w,h); out: (2000,7,7,256) f32.
//
// R8: counting-sort the 14000 (roi,py) pairs by key (ylo*150 + x) -- primary
// source row, secondary column -- so each XCD's walk of its sorted chunk reads
// the image in quasi-sequential order (row-buffer-friendly HBM fetch, L1 reuse
// across x-adjacent pairs). K2: one pair per wave, fully unrolled px loop,
// bijective XCD-chunked swizzle, NT stores.

typedef float f32x4 __attribute__((ext_vector_type(4)));

#define NBINS        30000   // ylo in [0,200) * 150 + x in [0,150)
#define SORT_THREADS 1024
#define SCAN_THREADS 768
#define BPT          40      // bins per scan thread: 768*40 = 30720 >= 30000

// ---- K1: counting sort of pairs by (ylo,x) into perm (d_ws) -----------------
__global__ __launch_bounds__(SORT_THREADS) void roi_sort_kernel(
    const int* __restrict__ rois, int R, int* __restrict__ perm)
{
    __shared__ int cnt[NBINS];
    __shared__ int partials[SCAN_THREADS];
    const int tid   = threadIdx.x;
    const int pairs = R * 7;

    for (int b = tid; b < NBINS; b += SORT_THREADS) cnt[b] = 0;
    __syncthreads();

    // histogram
    for (int p = tid; p < pairs; p += SORT_THREADS) {
        const int r  = p / 7;
        const int py = p - r * 7;
        const int x  = rois[4 * r + 0];
        const int y  = rois[4 * r + 1];
        const int h  = rois[4 * r + 3];
        const float ty = ((float)py + 0.5f) * ((float)h / 7.0f) - 0.5f;
        const int  iy  = (int)floorf(ty);
        const int  ylo = min(max(iy, 0), h - 1) + y;          // [0,199]
        const int  key = ylo * 150 + min(x, 149);
        atomicAdd(&cnt[key], 1);
    }
    __syncthreads();

    // exclusive scan over 30000 bins: per-thread serial + wave scan of partials
    if (tid < SCAN_THREADS) {
        int s = 0;
        const int b0 = tid * BPT;
        for (int i = 0; i < BPT; ++i) {
            const int b = b0 + i;
            if (b < NBINS) { const int v = cnt[b]; cnt[b] = s; s += v; }
        }
        partials[tid] = s;
    }
    __syncthreads();
    if (tid < 64) {                       // wave 0: scan the 768 partials
        int tot = 0;
        const int p0 = tid * (SCAN_THREADS / 64);   // 12 per lane
        for (int j = 0; j < SCAN_THREADS / 64; ++j) tot += partials[p0 + j];
        int inc = tot;
        for (int off = 1; off < 64; off <<= 1) {
            const int v = __shfl_up(inc, off);
            if (tid >= off) inc += v;
        }
        int run = inc - tot;              // exclusive prefix of this lane's chunk
        for (int j = 0; j < SCAN_THREADS / 64; ++j) {
            const int v = partials[p0 + j];
            partials[p0 + j] = run;
            run += v;
        }
    }
    __syncthreads();
    if (tid < SCAN_THREADS) {
        const int base = partials[tid];
        const int b0   = tid * BPT;
        for (int i = 0; i < BPT; ++i) {
            const int b = b0 + i;
            if (b < NBINS) cnt[b] += base;
        }
    }
    __syncthreads();

    // scatter (order within a bin arbitrary; output is order-invariant)
    for (int p = tid; p < pairs; p += SORT_THREADS) {
        const int r  = p / 7;
        const int py = p - r * 7;
        const int x  = rois[4 * r + 0];
        const int y  = rois[4 * r + 1];
        const int h  = rois[4 * r + 3];
        const float ty = ((float)py + 0.5f) * ((float)h / 7.0f) - 0.5f;
        const int  iy  = (int)floorf(ty);
        const int  ylo = min(max(iy, 0), h - 1) + y;
        const int  key = ylo * 150 + min(x, 149);
        const int  pos = atomicAdd(&cnt[key], 1);
        perm[pos] = p;
    }
}

// ---- K2: main kernel, 1 sorted pair per wave, 4 per block -------------------
__global__ __launch_bounds__(256) void roi_pool_kernel(
    const float* __restrict__ img,
    const int*   __restrict__ rois,
    const int*   __restrict__ perm,
    float*       __restrict__ out,
    int npairs)
{
    constexpr int P = 7;
    constexpr int C = 256;
    constexpr int W = 200;

    // bijective XCD-chunk swizzle (m204): each XCD owns a contiguous chunk
    const int nwg  = gridDim.x;
    const int q    = nwg >> 3;
    const int rr   = nwg & 7;
    const int xcd  = blockIdx.x & 7;
    const int base = (xcd < rr) ? xcd * (q + 1) : rr * (q + 1) + (xcd - rr) * q;
    const int bid  = base + (blockIdx.x >> 3);

    const int wave = threadIdx.x >> 6;
    const int c    = (threadIdx.x & 63) << 2;      // 4 channels/lane

    const int pidx = bid * 4 + wave;
    if (pidx >= npairs) return;

    const int p  = perm[pidx];
    const int r  = p / 7;
    const int py = p - r * 7;

    const int x = rois[4 * r + 0];
    const int y = rois[4 * r + 1];
    const int w = rois[4 * r + 2];
    const int h = rois[4 * r + 3];

    const float ty = ((float)py + 0.5f) * ((float)h / (float)P) - 0.5f;
    const float fy = floorf(ty);
    const float wy = ty - fy;
    const int   iy = (int)fy;
    const int   ylo = min(max(iy,     0), h - 1) + y;
    const int   yhi = min(max(iy + 1, 0), h - 1) + y;

    const float* row0 = img + (long)ylo * W * C + c;
    const float* row1 = img + (long)yhi * W * C + c;
    const float  sx   = (float)w / (float)P;

    float* out_row = out + ((long)r * P + py) * P * C + c;

    #pragma unroll
    for (int px = 0; px < P; ++px) {
        const float tx = ((float)px + 0.5f) * sx - 0.5f;
        const float fx = floorf(tx);
        const float wx = tx - fx;
        const int   ix = (int)fx;
        const int   xlo = min(max(ix,     0), w - 1) + x;
        const int   xhi = min(max(ix + 1, 0), w - 1) + x;

        const f32x4 v00 = *(const f32x4*)(row0 + xlo * C);
        const f32x4 v01 = *(const f32x4*)(row0 + xhi * C);
        const f32x4 v10 = *(const f32x4*)(row1 + xlo * C);
        const f32x4 v11 = *(const f32x4*)(row1 + xhi * C);

        const f32x4 top = v00 + (v01 - v00) * wx;
        const f32x4 bot = v10 + (v11 - v10) * wx;
        const f32x4 res = top + (bot - top) * wy;

        __builtin_nontemporal_store(res, (f32x4*)(out_row + px * C));
    }
}

extern "C" void kernel_launch(void* const* d_in, const int* in_sizes, int n_in,
                              void* d_out, int out_size, void* d_ws, size_t ws_size,
                              hipStream_t stream) {
    const float* img  = (const float*)d_in[0];
    const int*   rois = (const int*)d_in[1];
    float*       out  = (float*)d_out;
    int*         perm = (int*)d_ws;

    const int R      = in_sizes[1] / 4;   // 2000
    const int npairs = R * 7;             // 14000
    const int blocks = (npairs + 3) / 4;  // 3500 (1 pair per wave, 4 waves/block)

    roi_sort_kernel<<<1, SORT_THREADS, 0, stream>>>(rois, R, perm);
    roi_pool_kernel<<<blocks, 256, 0, stream>>>(img, rois, perm, out, npairs);
}

// Round 10
// 46.845 us; speedup vs baseline: 1.2633x; 1.2633x over previous
//
#include <hip/hip_runtime.h>

// ROI pooling: bilinear resize each (h,w) crop to 7x7 over 256 channels.
// img: (200,200,256) f32 NHWC; rois: (2000,4) int32 (x,y,w,h); out: (2000,7,7,256) f32.
//
// R9 structure (resubmitted unchanged after infra failure):
//  K1: counting-sort the 14000 (roi,py) pairs by source row ylo (200 bins,
//      1 block, wave-parallel scan).
//  K2: 1750 blocks x 4 waves x exactly 2 sorted pairs per wave (zero tail,
//      zero imbalance). __launch_bounds__(256,7) caps VGPR so 7 blocks/CU
//      co-reside -> the whole grid is ONE batch (1792 slots >= 1750 blocks).
//      Bijective XCD-chunked swizzle keeps each XCD on a contiguous run of
//      sorted pairs (instantaneous footprint ~few rows -> L2-resident).
//      NT stores keep the 98 MB output stream from evicting the image.

typedef float f32x4 __attribute__((ext_vector_type(4)));

// ---- K1: counting sort of pairs by ylo into perm (d_ws) ---------------------
__global__ __launch_bounds__(1024) void roi_sort_kernel(
    const int* __restrict__ rois, int R, int* __restrict__ perm)
{
    __shared__ int cnt[256];
    const int tid   = threadIdx.x;
    const int pairs = R * 7;

    if (tid < 256) cnt[tid] = 0;
    __syncthreads();

    // histogram of ylo
    for (int p = tid; p < pairs; p += 1024) {
        const int r  = p / 7;
        const int py = p - r * 7;
        const int y  = rois[4 * r + 1];
        const int h  = rois[4 * r + 3];
        const float ty = ((float)py + 0.5f) * ((float)h / 7.0f) - 0.5f;
        const int  iy  = (int)floorf(ty);
        const int  ylo = min(max(iy, 0), h - 1) + y;   // in [0,199]
        atomicAdd(&cnt[ylo], 1);
    }
    __syncthreads();

    // exclusive scan over 256 bins: wave 0, 4 bins/lane + shfl_up scan
    if (tid < 64) {
        const int b  = tid << 2;
        const int v0 = cnt[b], v1 = cnt[b + 1], v2 = cnt[b + 2], v3 = cnt[b + 3];
        const int tot = v0 + v1 + v2 + v3;
        int inc = tot;
        #pragma unroll
        for (int off = 1; off < 64; off <<= 1) {
            const int t = __shfl_up(inc, off);
            if (tid >= off) inc += t;
        }
        const int excl = inc - tot;
        cnt[b]     = excl;
        cnt[b + 1] = excl + v0;
        cnt[b + 2] = excl + v0 + v1;
        cnt[b + 3] = excl + v0 + v1 + v2;
    }
    __syncthreads();

    // scatter (order within a bin arbitrary; output is order-invariant)
    for (int p = tid; p < pairs; p += 1024) {
        const int r  = p / 7;
        const int py = p - r * 7;
        const int y  = rois[4 * r + 1];
        const int h  = rois[4 * r + 3];
        const float ty = ((float)py + 0.5f) * ((float)h / 7.0f) - 0.5f;
        const int  iy  = (int)floorf(ty);
        const int  ylo = min(max(iy, 0), h - 1) + y;
        const int  pos = atomicAdd(&cnt[ylo], 1);
        perm[pos] = p;
    }
}

// ---- K2: 2 sorted pairs per wave, 8 per block, single co-resident batch -----
__global__ __launch_bounds__(256, 7) void roi_pool_kernel(
    const float* __restrict__ img,
    const int*   __restrict__ rois,
    const int*   __restrict__ perm,
    float*       __restrict__ out,
    int npairs)
{
    constexpr int P = 7;
    constexpr int C = 256;
    constexpr int W = 200;

    // bijective XCD-chunk swizzle (m204): each XCD owns a contiguous chunk
    const int nwg  = gridDim.x;
    const int q    = nwg >> 3;
    const int rr   = nwg & 7;
    const int xcd  = blockIdx.x & 7;
    const int base = (xcd < rr) ? xcd * (q + 1) : rr * (q + 1) + (xcd - rr) * q;
    const int bid  = base + (blockIdx.x >> 3);

    const int wave = threadIdx.x >> 6;
    const int c    = (threadIdx.x & 63) << 2;      // 4 channels/lane

    for (int k = 0; k < 2; ++k) {
        const int pidx = bid * 8 + wave * 2 + k;   // 2 consecutive sorted pairs
        if (pidx >= npairs) return;

        const int p  = perm[pidx];
        const int r  = p / 7;
        const int py = p - r * 7;

        const int x = rois[4 * r + 0];
        const int y = rois[4 * r + 1];
        const int w = rois[4 * r + 2];
        const int h = rois[4 * r + 3];

        const float ty = ((float)py + 0.5f) * ((float)h / (float)P) - 0.5f;
        const float fy = floorf(ty);
        const float wy = ty - fy;
        const int   iy = (int)fy;
        const int   ylo = min(max(iy,     0), h - 1) + y;
        const int   yhi = min(max(iy + 1, 0), h - 1) + y;

        const float* row0 = img + (long)ylo * W * C + c;
        const float* row1 = img + (long)yhi * W * C + c;
        const float  sx   = (float)w / (float)P;

        float* out_row = out + ((long)r * P + py) * P * C + c;

        #pragma unroll
        for (int px = 0; px < P; ++px) {
            const float tx = ((float)px + 0.5f) * sx - 0.5f;
            const float fx = floorf(tx);
            const float wx = tx - fx;
            const int   ix = (int)fx;
            const int   xlo = min(max(ix,     0), w - 1) + x;
            const int   xhi = min(max(ix + 1, 0), w - 1) + x;

            const f32x4 v00 = *(const f32x4*)(row0 + xlo * C);
            const f32x4 v01 = *(const f32x4*)(row0 + xhi * C);
            const f32x4 v10 = *(const f32x4*)(row1 + xlo * C);
            const f32x4 v11 = *(const f32x4*)(row1 + xhi * C);

            const f32x4 top = v00 + (v01 - v00) * wx;
            const f32x4 bot = v10 + (v11 - v10) * wx;
            const f32x4 res = top + (bot - top) * wy;

            __builtin_nontemporal_store(res, (f32x4*)(out_row + px * C));
        }
    }
}

extern "C" void kernel_launch(void* const* d_in, const int* in_sizes, int n_in,
                              void* d_out, int out_size, void* d_ws, size_t ws_size,
                              hipStream_t stream) {
    const float* img  = (const float*)d_in[0];
    const int*   rois = (const int*)d_in[1];
    float*       out  = (float*)d_out;
    int*         perm = (int*)d_ws;

    const int R      = in_sizes[1] / 4;   // 2000
    const int npairs = R * 7;             // 14000
    const int blocks = (npairs + 7) / 8;  // 1750: 4 waves x 2 pairs per block

    roi_sort_kernel<<<1, 1024, 0, stream>>>(rois, R, perm);
    roi_pool_kernel<<<blocks, 256, 0, stream>>>(img, rois, perm, out, npairs);
}